// Round 15
// baseline (184.446 us; speedup 1.0000x reference)
//
#include <hip/hip_runtime.h>
#include <math.h>

// RelationalKENN R21: SINGLE-PASS bin — static per-(block,bin) entry regions
// kill pass 1, the LDS index cache, and the cursor reserve entirely.
//
// Ledger:
//  R10 global u64 atomics ✗ (287us). R11/R16 NB=1024 ✗✗ (L2-capacity).
//  R12 fusion ✗. R13b nt-everything: split (nt loads WIN / nt scatter-store ✗).
//  R14 nt loads+out_b ✓ 190.3. R15 pass-2-atomic-removal ∅. R17 TILE_N=200
//  wash. R18 12B entries + 1024-thr acc ✓ 185.4. R19 replicated acc ∅.
//  R20 ILP-4 ✓ 183.0 BEST (bin 85.8).
//  R21: bin's 2 sweeps exist only to pre-size contiguous per-tile entry
//      ranges. Static regions entries[(t*NB+blk)*CAP+slot], CAP=38
//      (lambda=2*chunk/T=25, +2.7 sigma; overflow ->exact fp32 atomics,
//      ~700 sides expected) make the count atomic's return value the slot:
//      single sweep, 2 (not 4) LDS atomics/edge, no cursor, 1KB LDS.
//      acc reads tile regions coalesced with slot<cnt[blk] validity check
//      (58.4MB vs 38.4MB, +3us). ws 62.1MB <= 62.9MB proven (R9).
//      Predict bin ->62-72, total ->168-176. Falsifier: bin >=82 =>
//      pass 1 was latency-hidden => structure converged, declare roofline.

#define NU 16
#define NC 8
#define TILE_N 400u
#define NB 512        // bin-pass blocks
#define BT 512        // bin-pass block size
#define ACC_ST 400
#define BTA 1024      // tile_acc block size
#define CAP 38        // per-(block,bin) entry capacity (lambda=25 + 2.7sigma)

typedef float    f32x4 __attribute__((ext_vector_type(4)));
typedef unsigned u32x4 __attribute__((ext_vector_type(4)));

__device__ __forceinline__ int q10(float x) {
    int q = __float2int_rn(x * 512.0f);
    q = q < -511 ? -511 : (q > 511 ? 511 : q);
    return q & 0x3FF;
}
__device__ __forceinline__ int sx10(unsigned w, int sh) {
    return ((int)(w << (22 - sh))) >> 22;
}
__device__ __forceinline__ unsigned long long pk4(int a0, int a1, int a2, int a3) {
    return (unsigned long long)(long long)a0 +
           ((unsigned long long)(long long)a1 << 16) +
           ((unsigned long long)(long long)a2 << 32) +
           ((unsigned long long)(unsigned short)a3 << 48);
}

__global__ void unary_enhance_kernel(const float* __restrict__ unary,
                                     const float* __restrict__ ucw,
                                     float* __restrict__ out_u,   // [n_nodes*16]
                                     float* __restrict__ u_lo,    // [n_nodes*8]
                                     int n_nodes) {
    int n = blockIdx.x * blockDim.x + threadIdx.x;
    if (n >= n_nodes) return;

    float x[NU];
    const float4* src = (const float4*)(unary + (size_t)n * NU);
#pragma unroll
    for (int j = 0; j < 4; ++j) {
        float4 v = src[j];
        x[4*j+0] = v.x; x[4*j+1] = v.y; x[4*j+2] = v.z; x[4*j+3] = v.w;
    }
    float dlt[NU];
#pragma unroll
    for (int j = 0; j < NU; ++j) dlt[j] = 0.0f;
#pragma unroll
    for (int i = 0; i < NC; ++i) {
        float w = ucw[i];
        float a = -x[i], b = x[i+1], c = x[i+2];
        float m = fmaxf(a, fmaxf(b, c));
        float e0 = __expf(a - m);
        float e1 = __expf(b - m);
        float e2 = __expf(c - m);
        float inv = 1.0f / (e0 + e1 + e2);
        dlt[i]   -= w * e0 * inv;
        dlt[i+1] += w * e1 * inv;
        dlt[i+2] += w * e2 * inv;
    }
    float u[NU];
#pragma unroll
    for (int j = 0; j < NU; ++j) u[j] = x[j] + dlt[j];

    float4* dst = (float4*)(out_u + (size_t)n * NU);
#pragma unroll
    for (int j = 0; j < 4; ++j) {
        float4 v; v.x = u[4*j+0]; v.y = u[4*j+1]; v.z = u[4*j+2]; v.w = u[4*j+3];
        dst[j] = v;
    }
    // u_lo: NORMAL store — we WANT it resident in L2 for bin's gathers.
    float4* lo = (float4*)(u_lo + (size_t)n * 8);
    float4 l0; l0.x = u[0]; l0.y = u[1]; l0.z = u[2]; l0.w = u[3];
    float4 l1; l1.x = u[4]; l1.y = u[5]; l1.z = u[6]; l1.w = u[7];
    lo[0] = l0; lo[1] = l1;
}

// Softmax + out_b + 2 scatter entries (12B) for one edge; slot comes
// directly from the LDS histogram atomic (single-pass scheme).
__device__ __forceinline__ void edge_body(int e, int i1, int i2, f32x4 bv,
                                          float4 a0, float4 a1, float4 c0, float4 c1,
                                          const float* w,
                                          float* __restrict__ out_b,
                                          unsigned* hist,
                                          unsigned* __restrict__ eblk, // entries + blk*CAP*3
                                          float* __restrict__ out_u) {
    float b[4] = {bv.x, bv.y, bv.z, bv.w};
    float u1[8] = {a0.x,a0.y,a0.z,a0.w,a1.x,a1.y,a1.z,a1.w};
    float u2[8] = {c0.x,c0.y,c0.z,c0.w,c1.x,c1.y,c1.z,c1.w};

    float d1[8], d2[8], dbp[4] = {0.f,0.f,0.f,0.f};
#pragma unroll
    for (int i = 0; i < NC; ++i) {
        float a = -u1[i], bb = b[i & 3], c = u2[i];
        float m = fmaxf(a, fmaxf(bb, c));
        float e0x = __expf(a - m);
        float e1x = __expf(bb - m);
        float e2x = __expf(c - m);
        float inv = 1.0f / (e0x + e1x + e2x);
        d1[i] = -w[i] * e0x * inv;
        d2[i] =  w[i] * e2x * inv;
        dbp[i & 3] += w[i] * e1x * inv;
    }
    f32x4 ob;
    ob.x = b[0] + dbp[0];
    ob.y = b[1] + dbp[1];
    ob.z = b[2] + dbp[2];
    ob.w = b[3] + dbp[3];
    __builtin_nontemporal_store(ob, ((f32x4*)out_b) + e);

    unsigned t1 = (unsigned)i1 / TILE_N;
    unsigned id1 = (unsigned)i1 - t1 * TILE_N;
    unsigned slot1 = atomicAdd(&hist[t1], 1u);
    if (slot1 < (unsigned)CAP) {
        unsigned* ep = eblk + ((size_t)t1 * (NB * CAP) + slot1) * 3;
        ep[0] = (unsigned)q10(d1[0]) | ((unsigned)q10(d1[1]) << 10) | ((unsigned)q10(d1[2]) << 20);
        ep[1] = (unsigned)q10(d1[3]) | ((unsigned)q10(d1[4]) << 10) | ((unsigned)q10(d1[5]) << 20);
        ep[2] = (unsigned)q10(d1[6]) | ((unsigned)q10(d1[7]) << 10) | (id1 << 20);
    } else {
        float* r = out_u + (size_t)i1 * NU;
#pragma unroll
        for (int i = 0; i < NC; ++i) atomicAdd(r + i, d1[i]);
    }

    unsigned t2 = (unsigned)i2 / TILE_N;
    unsigned id2 = (unsigned)i2 - t2 * TILE_N;
    unsigned slot2 = atomicAdd(&hist[t2], 1u);
    if (slot2 < (unsigned)CAP) {
        unsigned* ep = eblk + ((size_t)t2 * (NB * CAP) + slot2) * 3;
        ep[0] = (unsigned)q10(d2[0]) | ((unsigned)q10(d2[1]) << 10) | ((unsigned)q10(d2[2]) << 20);
        ep[1] = (unsigned)q10(d2[3]) | ((unsigned)q10(d2[4]) << 10) | ((unsigned)q10(d2[5]) << 20);
        ep[2] = (unsigned)q10(d2[6]) | ((unsigned)q10(d2[7]) << 10) | (id2 << 20);
    } else {
        float* r = out_u + (size_t)i2 * NU;
#pragma unroll
        for (int i = 0; i < NC; ++i) atomicAdd(r + i, d2[i]);
    }
}

__global__ __launch_bounds__(BT, 4)
void bin_edges_kernel(const float* __restrict__ binary,
                      const float* __restrict__ bcw,
                      const int* __restrict__ index1,
                      const int* __restrict__ index2,
                      const float* __restrict__ u_lo,
                      float* __restrict__ out_b,       // [n_edges*4]
                      unsigned* __restrict__ counts,   // [T*NB]
                      unsigned* __restrict__ entries,  // [T*NB*CAP*3 u32]
                      float* __restrict__ out_u,       // overflow path only
                      int n_edges, int T, int chunk) {
    __shared__ unsigned hist[256];
    int tid = threadIdx.x;
    for (int t = tid; t < T; t += BT) hist[t] = 0u;
    __syncthreads();

    int e0 = blockIdx.x * chunk;
    int e1 = e0 + chunk; if (e1 > n_edges) e1 = n_edges;

    unsigned* eblk = entries + (size_t)blockIdx.x * CAP * 3;

    float w[NC];
#pragma unroll
    for (int i = 0; i < NC; ++i) w[i] = bcw[i];

    // single pass, 4x unrolled — four independent gather chains in flight.
    int eA = e0 + tid;
    for (; eA + 3 * BT < e1; eA += 4 * BT) {
        int eB = eA + BT, eC = eA + 2 * BT, eD = eA + 3 * BT;
        int i1A = __builtin_nontemporal_load(index1 + eA);
        int i2A = __builtin_nontemporal_load(index2 + eA);
        int i1B = __builtin_nontemporal_load(index1 + eB);
        int i2B = __builtin_nontemporal_load(index2 + eB);
        int i1C = __builtin_nontemporal_load(index1 + eC);
        int i2C = __builtin_nontemporal_load(index2 + eC);
        int i1D = __builtin_nontemporal_load(index1 + eD);
        int i2D = __builtin_nontemporal_load(index2 + eD);

        f32x4 bvA = __builtin_nontemporal_load(((const f32x4*)binary) + eA);
        f32x4 bvB = __builtin_nontemporal_load(((const f32x4*)binary) + eB);
        f32x4 bvC = __builtin_nontemporal_load(((const f32x4*)binary) + eC);
        f32x4 bvD = __builtin_nontemporal_load(((const f32x4*)binary) + eD);

        const float4* p1A = (const float4*)(u_lo + (size_t)i1A * 8);
        const float4* p2A = (const float4*)(u_lo + (size_t)i2A * 8);
        const float4* p1B = (const float4*)(u_lo + (size_t)i1B * 8);
        const float4* p2B = (const float4*)(u_lo + (size_t)i2B * 8);
        const float4* p1C = (const float4*)(u_lo + (size_t)i1C * 8);
        const float4* p2C = (const float4*)(u_lo + (size_t)i2C * 8);
        const float4* p1D = (const float4*)(u_lo + (size_t)i1D * 8);
        const float4* p2D = (const float4*)(u_lo + (size_t)i2D * 8);
        float4 a0A = p1A[0], a1A = p1A[1], c0A = p2A[0], c1A = p2A[1];
        float4 a0B = p1B[0], a1B = p1B[1], c0B = p2B[0], c1B = p2B[1];
        float4 a0C = p1C[0], a1C = p1C[1], c0C = p2C[0], c1C = p2C[1];
        float4 a0D = p1D[0], a1D = p1D[1], c0D = p2D[0], c1D = p2D[1];

        edge_body(eA, i1A, i2A, bvA, a0A, a1A, c0A, c1A, w, out_b, hist, eblk, out_u);
        edge_body(eB, i1B, i2B, bvB, a0B, a1B, c0B, c1B, w, out_b, hist, eblk, out_u);
        edge_body(eC, i1C, i2C, bvC, a0C, a1C, c0C, c1C, w, out_b, hist, eblk, out_u);
        edge_body(eD, i1D, i2D, bvD, a0D, a1D, c0D, c1D, w, out_b, hist, eblk, out_u);
    }
    for (; eA < e1; eA += BT) {
        int i1A = __builtin_nontemporal_load(index1 + eA);
        int i2A = __builtin_nontemporal_load(index2 + eA);
        f32x4 bvA = __builtin_nontemporal_load(((const f32x4*)binary) + eA);
        const float4* p1A = (const float4*)(u_lo + (size_t)i1A * 8);
        const float4* p2A = (const float4*)(u_lo + (size_t)i2A * 8);
        float4 a0A = p1A[0], a1A = p1A[1];
        float4 c0A = p2A[0], c1A = p2A[1];
        edge_body(eA, i1A, i2A, bvA, a0A, a1A, c0A, c1A, w, out_b, hist, eblk, out_u);
    }
    __syncthreads();

    // publish per-(block,bin) counts (acc clamps to CAP)
    for (int t = tid; t < T; t += BT) counts[(size_t)t * NB + blockIdx.x] = hist[t];
}

// Accumulate pass: sweep the tile's full static region (NB*CAP slots)
// coalesced; validity = slot < cnt[blk] from a 2KB LDS counts table.
__global__ __launch_bounds__(BTA)
void tile_acc_kernel(const unsigned* __restrict__ counts,
                     const unsigned* __restrict__ entries,
                     float* __restrict__ out_u,
                     int n_nodes) {
    __shared__ unsigned long long acc[2 * ACC_ST];
    __shared__ unsigned cnt[NB];
    int t = blockIdx.x;
    int tid = threadIdx.x;
    for (int i = tid; i < 2 * ACC_ST; i += BTA) acc[i] = 0ull;
    for (int i = tid; i < NB; i += BTA) {
        unsigned c = counts[(size_t)t * NB + i];
        cnt[i] = c > (unsigned)CAP ? (unsigned)CAP : c;
    }
    __syncthreads();

    const unsigned total = NB * CAP;                       // 19456, %4 == 0
    const unsigned* base = entries + (size_t)t * NB * CAP * 3;

    for (unsigned j4 = (unsigned)tid * 4; j4 < total; j4 += BTA * 4) {
        const u32x4* p = (const u32x4*)(base + (size_t)j4 * 3);
        u32x4 q0 = __builtin_nontemporal_load(p + 0);
        u32x4 q1 = __builtin_nontemporal_load(p + 1);
        u32x4 q2 = __builtin_nontemporal_load(p + 2);
        unsigned d[12] = {q0.x, q0.y, q0.z, q0.w,
                          q1.x, q1.y, q1.z, q1.w,
                          q2.x, q2.y, q2.z, q2.w};
#pragma unroll
        for (int k = 0; k < 4; ++k) {
            unsigned j = j4 + (unsigned)k;
            unsigned blk = j / (unsigned)CAP;              // compile-time divisor
            unsigned slot = j - blk * (unsigned)CAP;
            if (slot >= cnt[blk]) continue;
            unsigned wx = d[3*k], wy = d[3*k+1], wz = d[3*k+2];
            unsigned id = wz >> 20;
            unsigned long long lo = pk4(sx10(wx, 0), sx10(wx, 10), sx10(wx, 20), sx10(wy, 0));
            unsigned long long hi = pk4(sx10(wy, 10), sx10(wy, 20), sx10(wz, 0), sx10(wz, 10));
            atomicAdd(&acc[id], lo);
            atomicAdd(&acc[ACC_ST + id], hi);
        }
    }
    __syncthreads();

    const float INV = 1.0f / 512.0f;
    int nbase = t * (int)TILE_N;
    for (int l = tid; l < (int)TILE_N; l += BTA) {
        int n = nbase + l;
        if (n >= n_nodes) continue;
        float col[8];
#pragma unroll
        for (int wd = 0; wd < 2; ++wd) {
            unsigned long long S = acc[wd*ACC_ST + l];
#pragma unroll
            for (int f = 0; f < 4; ++f) {
                short s = (short)(S & 0xFFFFull);
                col[wd*4 + f] = (float)s * INV;
                S = (S - (unsigned long long)(long long)s) >> 16;
            }
        }
        float4* row = (float4*)(out_u + (size_t)n * NU);
        float4 r0 = row[0], r1 = row[1];
        r0.x += col[0]; r0.y += col[1]; r0.z += col[2]; r0.w += col[3];
        r1.x += col[4]; r1.y += col[5]; r1.z += col[6]; r1.w += col[7];
        row[0] = r0; row[1] = r1;
    }
}

// Fallback (R1): device-scope atomics, needs only u_lo in ws.
__global__ void edge_enhance_kernel(const float* __restrict__ binary,
                                    const float* __restrict__ bcw,
                                    const int* __restrict__ index1,
                                    const int* __restrict__ index2,
                                    const float* __restrict__ u_lo,
                                    float* __restrict__ out_u,
                                    float* __restrict__ out_b,
                                    int n_edges) {
    int e = blockIdx.x * blockDim.x + threadIdx.x;
    if (e >= n_edges) return;

    int i1 = index1[e];
    int i2 = index2[e];
    float4 bv = ((const float4*)binary)[e];
    float b[4] = {bv.x, bv.y, bv.z, bv.w};

    const float4* p1 = (const float4*)(u_lo + (size_t)i1 * 8);
    float4 a0 = p1[0], a1 = p1[1];
    const float4* p2 = (const float4*)(u_lo + (size_t)i2 * 8);
    float4 c0 = p2[0], c1 = p2[1];
    float u1[8] = {a0.x,a0.y,a0.z,a0.w,a1.x,a1.y,a1.z,a1.w};
    float u2[8] = {c0.x,c0.y,c0.z,c0.w,c1.x,c1.y,c1.z,c1.w};

    float d1[8], d2[8], dbp[4] = {0.f,0.f,0.f,0.f};
#pragma unroll
    for (int i = 0; i < NC; ++i) {
        float w = bcw[i];
        float a = -u1[i], bb = b[i & 3], c = u2[i];
        float m = fmaxf(a, fmaxf(bb, c));
        float e0 = __expf(a - m);
        float e1 = __expf(bb - m);
        float e2 = __expf(c - m);
        float inv = 1.0f / (e0 + e1 + e2);
        d1[i] = -w * e0 * inv;
        d2[i] =  w * e2 * inv;
        dbp[i & 3] += w * e1 * inv;
    }
    float* r1 = out_u + (size_t)i1 * NU;
#pragma unroll
    for (int i = 0; i < NC; ++i) atomicAdd(r1 + i, d1[i]);
    float* r2 = out_u + (size_t)i2 * NU;
#pragma unroll
    for (int i = 0; i < NC; ++i) atomicAdd(r2 + i, d2[i]);

    float4 ob;
    ob.x = b[0] + dbp[0];
    ob.y = b[1] + dbp[1];
    ob.z = b[2] + dbp[2];
    ob.w = b[3] + dbp[3];
    ((float4*)out_b)[e] = ob;
}

extern "C" void kernel_launch(void* const* d_in, const int* in_sizes, int n_in,
                              void* d_out, int out_size, void* d_ws, size_t ws_size,
                              hipStream_t stream) {
    const float* unary  = (const float*)d_in[0];
    const float* binary = (const float*)d_in[1];
    const float* ucw    = (const float*)d_in[2];
    const float* bcw    = (const float*)d_in[3];
    const int*   index1 = (const int*)d_in[4];
    const int*   index2 = (const int*)d_in[5];

    int n_nodes = in_sizes[0] / NU;
    int n_edges = in_sizes[4];

    float* out_u = (float*)d_out;
    float* out_b = out_u + (size_t)n_nodes * NU;

    int T = (int)(((unsigned)n_nodes + TILE_N - 1) / TILE_N);   // 250
    int chunk = (n_edges + NB - 1) / NB;                        // 3125

    // ws layout: u_lo [n_nodes*8 f32] | entries [T*NB*CAP*3 u32] | counts [T*NB u32]
    size_t u_lo_bytes  = (size_t)n_nodes * 8 * sizeof(float);
    size_t ent_off     = (u_lo_bytes + 63) & ~(size_t)63;
    size_t ent_bytes   = (size_t)T * NB * CAP * 12;
    size_t cnt_off     = ent_off + ent_bytes;
    size_t cnt_bytes   = (size_t)T * NB * 4;
    size_t need        = cnt_off + cnt_bytes;

    float* u_lo = (float*)d_ws;
    unsigned* entries = (unsigned*)((char*)d_ws + ent_off);
    unsigned* counts  = (unsigned*)((char*)d_ws + cnt_off);

    // lambda = 2*chunk/T must stay <= 25 for CAP=38 (+2.7 sigma)
    bool fast = (ws_size >= need && T <= 256 && 2 * chunk <= 25 * T + T / 8);

    int tb = 256;
    unary_enhance_kernel<<<(n_nodes + tb - 1) / tb, tb, 0, stream>>>(
        unary, ucw, out_u, u_lo, n_nodes);

    if (fast) {
        bin_edges_kernel<<<NB, BT, 0, stream>>>(
            binary, bcw, index1, index2, u_lo, out_b,
            counts, entries, out_u, n_edges, T, chunk);
        tile_acc_kernel<<<T, BTA, 0, stream>>>(
            counts, entries, out_u, n_nodes);
    } else {
        edge_enhance_kernel<<<(n_edges + tb - 1) / tb, tb, 0, stream>>>(
            binary, bcw, index1, index2, u_lo, out_u, out_b, n_edges);
    }
}

// Round 16
// 180.894 us; speedup vs baseline: 1.0196x; 1.0196x over previous
//
#include <hip/hip_runtime.h>
#include <math.h>

// RelationalKENN R22: R21 single-pass bin + acc group-skip (skip provably
// all-invalid 4-entry groups before loading).
//
// Ledger:
//  R10 global u64 atomics ✗. R11/R16 NB=1024 ✗✗ (L2-capacity). R12 fusion ✗.
//  R13b nt split (loads ✓ / scatter-store ✗). R14 ✓ 190.3. R15 ∅.
//  R17 TILE_N=200 wash. R18 12B entries ✓ 185.4. R19 replicated acc ∅.
//  R20 ILP-4 ✓ 183.0 (bin 85.8). R21 single-pass bin: bin ✓ 80.5
//      (bank-conflicts halved) but acc sweep +6.7us -> total 184.4.
//  R22: slots fill from 0, so group with slot0 >= cnt[blk] (not crossing
//      into a non-empty cell) is all-invalid -> skip 3 nt loads. ~30% of
//      groups skipped (~17MB). Predict bin ~80.5 flat, acc -3..5us,
//      total ->179-181. Falsifier: total >=183 => converged at ~183,
//      declare roofline.

#define NU 16
#define NC 8
#define TILE_N 400u
#define NB 512        // bin-pass blocks
#define BT 512        // bin-pass block size
#define ACC_ST 400
#define BTA 1024      // tile_acc block size
#define CAP 38        // per-(block,bin) entry capacity (lambda=25 + 2.7sigma)

typedef float    f32x4 __attribute__((ext_vector_type(4)));
typedef unsigned u32x4 __attribute__((ext_vector_type(4)));

__device__ __forceinline__ int q10(float x) {
    int q = __float2int_rn(x * 512.0f);
    q = q < -511 ? -511 : (q > 511 ? 511 : q);
    return q & 0x3FF;
}
__device__ __forceinline__ int sx10(unsigned w, int sh) {
    return ((int)(w << (22 - sh))) >> 22;
}
__device__ __forceinline__ unsigned long long pk4(int a0, int a1, int a2, int a3) {
    return (unsigned long long)(long long)a0 +
           ((unsigned long long)(long long)a1 << 16) +
           ((unsigned long long)(long long)a2 << 32) +
           ((unsigned long long)(unsigned short)a3 << 48);
}

__global__ void unary_enhance_kernel(const float* __restrict__ unary,
                                     const float* __restrict__ ucw,
                                     float* __restrict__ out_u,   // [n_nodes*16]
                                     float* __restrict__ u_lo,    // [n_nodes*8]
                                     int n_nodes) {
    int n = blockIdx.x * blockDim.x + threadIdx.x;
    if (n >= n_nodes) return;

    float x[NU];
    const float4* src = (const float4*)(unary + (size_t)n * NU);
#pragma unroll
    for (int j = 0; j < 4; ++j) {
        float4 v = src[j];
        x[4*j+0] = v.x; x[4*j+1] = v.y; x[4*j+2] = v.z; x[4*j+3] = v.w;
    }
    float dlt[NU];
#pragma unroll
    for (int j = 0; j < NU; ++j) dlt[j] = 0.0f;
#pragma unroll
    for (int i = 0; i < NC; ++i) {
        float w = ucw[i];
        float a = -x[i], b = x[i+1], c = x[i+2];
        float m = fmaxf(a, fmaxf(b, c));
        float e0 = __expf(a - m);
        float e1 = __expf(b - m);
        float e2 = __expf(c - m);
        float inv = 1.0f / (e0 + e1 + e2);
        dlt[i]   -= w * e0 * inv;
        dlt[i+1] += w * e1 * inv;
        dlt[i+2] += w * e2 * inv;
    }
    float u[NU];
#pragma unroll
    for (int j = 0; j < NU; ++j) u[j] = x[j] + dlt[j];

    float4* dst = (float4*)(out_u + (size_t)n * NU);
#pragma unroll
    for (int j = 0; j < 4; ++j) {
        float4 v; v.x = u[4*j+0]; v.y = u[4*j+1]; v.z = u[4*j+2]; v.w = u[4*j+3];
        dst[j] = v;
    }
    // u_lo: NORMAL store — we WANT it resident in L2 for bin's gathers.
    float4* lo = (float4*)(u_lo + (size_t)n * 8);
    float4 l0; l0.x = u[0]; l0.y = u[1]; l0.z = u[2]; l0.w = u[3];
    float4 l1; l1.x = u[4]; l1.y = u[5]; l1.z = u[6]; l1.w = u[7];
    lo[0] = l0; lo[1] = l1;
}

// Softmax + out_b + 2 scatter entries (12B) for one edge; slot comes
// directly from the LDS histogram atomic (single-pass scheme).
__device__ __forceinline__ void edge_body(int e, int i1, int i2, f32x4 bv,
                                          float4 a0, float4 a1, float4 c0, float4 c1,
                                          const float* w,
                                          float* __restrict__ out_b,
                                          unsigned* hist,
                                          unsigned* __restrict__ eblk, // entries + blk*CAP*3
                                          float* __restrict__ out_u) {
    float b[4] = {bv.x, bv.y, bv.z, bv.w};
    float u1[8] = {a0.x,a0.y,a0.z,a0.w,a1.x,a1.y,a1.z,a1.w};
    float u2[8] = {c0.x,c0.y,c0.z,c0.w,c1.x,c1.y,c1.z,c1.w};

    float d1[8], d2[8], dbp[4] = {0.f,0.f,0.f,0.f};
#pragma unroll
    for (int i = 0; i < NC; ++i) {
        float a = -u1[i], bb = b[i & 3], c = u2[i];
        float m = fmaxf(a, fmaxf(bb, c));
        float e0x = __expf(a - m);
        float e1x = __expf(bb - m);
        float e2x = __expf(c - m);
        float inv = 1.0f / (e0x + e1x + e2x);
        d1[i] = -w[i] * e0x * inv;
        d2[i] =  w[i] * e2x * inv;
        dbp[i & 3] += w[i] * e1x * inv;
    }
    f32x4 ob;
    ob.x = b[0] + dbp[0];
    ob.y = b[1] + dbp[1];
    ob.z = b[2] + dbp[2];
    ob.w = b[3] + dbp[3];
    __builtin_nontemporal_store(ob, ((f32x4*)out_b) + e);

    unsigned t1 = (unsigned)i1 / TILE_N;
    unsigned id1 = (unsigned)i1 - t1 * TILE_N;
    unsigned slot1 = atomicAdd(&hist[t1], 1u);
    if (slot1 < (unsigned)CAP) {
        unsigned* ep = eblk + ((size_t)t1 * (NB * CAP) + slot1) * 3;
        ep[0] = (unsigned)q10(d1[0]) | ((unsigned)q10(d1[1]) << 10) | ((unsigned)q10(d1[2]) << 20);
        ep[1] = (unsigned)q10(d1[3]) | ((unsigned)q10(d1[4]) << 10) | ((unsigned)q10(d1[5]) << 20);
        ep[2] = (unsigned)q10(d1[6]) | ((unsigned)q10(d1[7]) << 10) | (id1 << 20);
    } else {
        float* r = out_u + (size_t)i1 * NU;
#pragma unroll
        for (int i = 0; i < NC; ++i) atomicAdd(r + i, d1[i]);
    }

    unsigned t2 = (unsigned)i2 / TILE_N;
    unsigned id2 = (unsigned)i2 - t2 * TILE_N;
    unsigned slot2 = atomicAdd(&hist[t2], 1u);
    if (slot2 < (unsigned)CAP) {
        unsigned* ep = eblk + ((size_t)t2 * (NB * CAP) + slot2) * 3;
        ep[0] = (unsigned)q10(d2[0]) | ((unsigned)q10(d2[1]) << 10) | ((unsigned)q10(d2[2]) << 20);
        ep[1] = (unsigned)q10(d2[3]) | ((unsigned)q10(d2[4]) << 10) | ((unsigned)q10(d2[5]) << 20);
        ep[2] = (unsigned)q10(d2[6]) | ((unsigned)q10(d2[7]) << 10) | (id2 << 20);
    } else {
        float* r = out_u + (size_t)i2 * NU;
#pragma unroll
        for (int i = 0; i < NC; ++i) atomicAdd(r + i, d2[i]);
    }
}

__global__ __launch_bounds__(BT, 4)
void bin_edges_kernel(const float* __restrict__ binary,
                      const float* __restrict__ bcw,
                      const int* __restrict__ index1,
                      const int* __restrict__ index2,
                      const float* __restrict__ u_lo,
                      float* __restrict__ out_b,       // [n_edges*4]
                      unsigned* __restrict__ counts,   // [T*NB]
                      unsigned* __restrict__ entries,  // [T*NB*CAP*3 u32]
                      float* __restrict__ out_u,       // overflow path only
                      int n_edges, int T, int chunk) {
    __shared__ unsigned hist[256];
    int tid = threadIdx.x;
    for (int t = tid; t < T; t += BT) hist[t] = 0u;
    __syncthreads();

    int e0 = blockIdx.x * chunk;
    int e1 = e0 + chunk; if (e1 > n_edges) e1 = n_edges;

    unsigned* eblk = entries + (size_t)blockIdx.x * CAP * 3;

    float w[NC];
#pragma unroll
    for (int i = 0; i < NC; ++i) w[i] = bcw[i];

    // single pass, 4x unrolled — four independent gather chains in flight.
    int eA = e0 + tid;
    for (; eA + 3 * BT < e1; eA += 4 * BT) {
        int eB = eA + BT, eC = eA + 2 * BT, eD = eA + 3 * BT;
        int i1A = __builtin_nontemporal_load(index1 + eA);
        int i2A = __builtin_nontemporal_load(index2 + eA);
        int i1B = __builtin_nontemporal_load(index1 + eB);
        int i2B = __builtin_nontemporal_load(index2 + eB);
        int i1C = __builtin_nontemporal_load(index1 + eC);
        int i2C = __builtin_nontemporal_load(index2 + eC);
        int i1D = __builtin_nontemporal_load(index1 + eD);
        int i2D = __builtin_nontemporal_load(index2 + eD);

        f32x4 bvA = __builtin_nontemporal_load(((const f32x4*)binary) + eA);
        f32x4 bvB = __builtin_nontemporal_load(((const f32x4*)binary) + eB);
        f32x4 bvC = __builtin_nontemporal_load(((const f32x4*)binary) + eC);
        f32x4 bvD = __builtin_nontemporal_load(((const f32x4*)binary) + eD);

        const float4* p1A = (const float4*)(u_lo + (size_t)i1A * 8);
        const float4* p2A = (const float4*)(u_lo + (size_t)i2A * 8);
        const float4* p1B = (const float4*)(u_lo + (size_t)i1B * 8);
        const float4* p2B = (const float4*)(u_lo + (size_t)i2B * 8);
        const float4* p1C = (const float4*)(u_lo + (size_t)i1C * 8);
        const float4* p2C = (const float4*)(u_lo + (size_t)i2C * 8);
        const float4* p1D = (const float4*)(u_lo + (size_t)i1D * 8);
        const float4* p2D = (const float4*)(u_lo + (size_t)i2D * 8);
        float4 a0A = p1A[0], a1A = p1A[1], c0A = p2A[0], c1A = p2A[1];
        float4 a0B = p1B[0], a1B = p1B[1], c0B = p2B[0], c1B = p2B[1];
        float4 a0C = p1C[0], a1C = p1C[1], c0C = p2C[0], c1C = p2C[1];
        float4 a0D = p1D[0], a1D = p1D[1], c0D = p2D[0], c1D = p2D[1];

        edge_body(eA, i1A, i2A, bvA, a0A, a1A, c0A, c1A, w, out_b, hist, eblk, out_u);
        edge_body(eB, i1B, i2B, bvB, a0B, a1B, c0B, c1B, w, out_b, hist, eblk, out_u);
        edge_body(eC, i1C, i2C, bvC, a0C, a1C, c0C, c1C, w, out_b, hist, eblk, out_u);
        edge_body(eD, i1D, i2D, bvD, a0D, a1D, c0D, c1D, w, out_b, hist, eblk, out_u);
    }
    for (; eA < e1; eA += BT) {
        int i1A = __builtin_nontemporal_load(index1 + eA);
        int i2A = __builtin_nontemporal_load(index2 + eA);
        f32x4 bvA = __builtin_nontemporal_load(((const f32x4*)binary) + eA);
        const float4* p1A = (const float4*)(u_lo + (size_t)i1A * 8);
        const float4* p2A = (const float4*)(u_lo + (size_t)i2A * 8);
        float4 a0A = p1A[0], a1A = p1A[1];
        float4 c0A = p2A[0], c1A = p2A[1];
        edge_body(eA, i1A, i2A, bvA, a0A, a1A, c0A, c1A, w, out_b, hist, eblk, out_u);
    }
    __syncthreads();

    // publish per-(block,bin) counts (acc clamps to CAP)
    for (int t = tid; t < T; t += BT) counts[(size_t)t * NB + blockIdx.x] = hist[t];
}

// Accumulate pass: sweep the tile's static region; SKIP provably-all-invalid
// 4-entry groups before loading (slots fill from 0 in each cell).
__global__ __launch_bounds__(BTA)
void tile_acc_kernel(const unsigned* __restrict__ counts,
                     const unsigned* __restrict__ entries,
                     float* __restrict__ out_u,
                     int n_nodes) {
    __shared__ unsigned long long acc[2 * ACC_ST];
    __shared__ unsigned cnt[NB];
    int t = blockIdx.x;
    int tid = threadIdx.x;
    for (int i = tid; i < 2 * ACC_ST; i += BTA) acc[i] = 0ull;
    for (int i = tid; i < NB; i += BTA) {
        unsigned c = counts[(size_t)t * NB + i];
        cnt[i] = c > (unsigned)CAP ? (unsigned)CAP : c;
    }
    __syncthreads();

    const unsigned total = NB * CAP;                       // 19456, %4 == 0
    const unsigned* base = entries + (size_t)t * NB * CAP * 3;

    for (unsigned j4 = (unsigned)tid * 4; j4 < total; j4 += BTA * 4) {
        // group-skip: all 4 slots invalid iff slot0 beyond cnt[b0] AND the
        // part (if any) spilling into cell b1 is beyond cnt[b1] (cells fill
        // from slot 0, so spill slots start at 0: invalid iff cnt[b1]==0).
        unsigned b0 = j4 / (unsigned)CAP;
        unsigned s0 = j4 - b0 * (unsigned)CAP;
        unsigned b1 = (j4 + 3u) / (unsigned)CAP;
        bool anyvalid = (s0 < cnt[b0]) || (b1 != b0 && cnt[b1] > 0u);
        if (!anyvalid) continue;

        const u32x4* p = (const u32x4*)(base + (size_t)j4 * 3);
        u32x4 q0 = __builtin_nontemporal_load(p + 0);
        u32x4 q1 = __builtin_nontemporal_load(p + 1);
        u32x4 q2 = __builtin_nontemporal_load(p + 2);
        unsigned d[12] = {q0.x, q0.y, q0.z, q0.w,
                          q1.x, q1.y, q1.z, q1.w,
                          q2.x, q2.y, q2.z, q2.w};
#pragma unroll
        for (int k = 0; k < 4; ++k) {
            unsigned j = j4 + (unsigned)k;
            unsigned blk = j / (unsigned)CAP;              // compile-time divisor
            unsigned slot = j - blk * (unsigned)CAP;
            if (slot >= cnt[blk]) continue;
            unsigned wx = d[3*k], wy = d[3*k+1], wz = d[3*k+2];
            unsigned id = wz >> 20;
            unsigned long long lo = pk4(sx10(wx, 0), sx10(wx, 10), sx10(wx, 20), sx10(wy, 0));
            unsigned long long hi = pk4(sx10(wy, 10), sx10(wy, 20), sx10(wz, 0), sx10(wz, 10));
            atomicAdd(&acc[id], lo);
            atomicAdd(&acc[ACC_ST + id], hi);
        }
    }
    __syncthreads();

    const float INV = 1.0f / 512.0f;
    int nbase = t * (int)TILE_N;
    for (int l = tid; l < (int)TILE_N; l += BTA) {
        int n = nbase + l;
        if (n >= n_nodes) continue;
        float col[8];
#pragma unroll
        for (int wd = 0; wd < 2; ++wd) {
            unsigned long long S = acc[wd*ACC_ST + l];
#pragma unroll
            for (int f = 0; f < 4; ++f) {
                short s = (short)(S & 0xFFFFull);
                col[wd*4 + f] = (float)s * INV;
                S = (S - (unsigned long long)(long long)s) >> 16;
            }
        }
        float4* row = (float4*)(out_u + (size_t)n * NU);
        float4 r0 = row[0], r1 = row[1];
        r0.x += col[0]; r0.y += col[1]; r0.z += col[2]; r0.w += col[3];
        r1.x += col[4]; r1.y += col[5]; r1.z += col[6]; r1.w += col[7];
        row[0] = r0; row[1] = r1;
    }
}

// Fallback (R1): device-scope atomics, needs only u_lo in ws.
__global__ void edge_enhance_kernel(const float* __restrict__ binary,
                                    const float* __restrict__ bcw,
                                    const int* __restrict__ index1,
                                    const int* __restrict__ index2,
                                    const float* __restrict__ u_lo,
                                    float* __restrict__ out_u,
                                    float* __restrict__ out_b,
                                    int n_edges) {
    int e = blockIdx.x * blockDim.x + threadIdx.x;
    if (e >= n_edges) return;

    int i1 = index1[e];
    int i2 = index2[e];
    float4 bv = ((const float4*)binary)[e];
    float b[4] = {bv.x, bv.y, bv.z, bv.w};

    const float4* p1 = (const float4*)(u_lo + (size_t)i1 * 8);
    float4 a0 = p1[0], a1 = p1[1];
    const float4* p2 = (const float4*)(u_lo + (size_t)i2 * 8);
    float4 c0 = p2[0], c1 = p2[1];
    float u1[8] = {a0.x,a0.y,a0.z,a0.w,a1.x,a1.y,a1.z,a1.w};
    float u2[8] = {c0.x,c0.y,c0.z,c0.w,c1.x,c1.y,c1.z,c1.w};

    float d1[8], d2[8], dbp[4] = {0.f,0.f,0.f,0.f};
#pragma unroll
    for (int i = 0; i < NC; ++i) {
        float w = bcw[i];
        float a = -u1[i], bb = b[i & 3], c = u2[i];
        float m = fmaxf(a, fmaxf(bb, c));
        float e0 = __expf(a - m);
        float e1 = __expf(bb - m);
        float e2 = __expf(c - m);
        float inv = 1.0f / (e0 + e1 + e2);
        d1[i] = -w * e0 * inv;
        d2[i] =  w * e2 * inv;
        dbp[i & 3] += w * e1 * inv;
    }
    float* r1 = out_u + (size_t)i1 * NU;
#pragma unroll
    for (int i = 0; i < NC; ++i) atomicAdd(r1 + i, d1[i]);
    float* r2 = out_u + (size_t)i2 * NU;
#pragma unroll
    for (int i = 0; i < NC; ++i) atomicAdd(r2 + i, d2[i]);

    float4 ob;
    ob.x = b[0] + dbp[0];
    ob.y = b[1] + dbp[1];
    ob.z = b[2] + dbp[2];
    ob.w = b[3] + dbp[3];
    ((float4*)out_b)[e] = ob;
}

extern "C" void kernel_launch(void* const* d_in, const int* in_sizes, int n_in,
                              void* d_out, int out_size, void* d_ws, size_t ws_size,
                              hipStream_t stream) {
    const float* unary  = (const float*)d_in[0];
    const float* binary = (const float*)d_in[1];
    const float* ucw    = (const float*)d_in[2];
    const float* bcw    = (const float*)d_in[3];
    const int*   index1 = (const int*)d_in[4];
    const int*   index2 = (const int*)d_in[5];

    int n_nodes = in_sizes[0] / NU;
    int n_edges = in_sizes[4];

    float* out_u = (float*)d_out;
    float* out_b = out_u + (size_t)n_nodes * NU;

    int T = (int)(((unsigned)n_nodes + TILE_N - 1) / TILE_N);   // 250
    int chunk = (n_edges + NB - 1) / NB;                        // 3125

    // ws layout: u_lo [n_nodes*8 f32] | entries [T*NB*CAP*3 u32] | counts [T*NB u32]
    size_t u_lo_bytes  = (size_t)n_nodes * 8 * sizeof(float);
    size_t ent_off     = (u_lo_bytes + 63) & ~(size_t)63;
    size_t ent_bytes   = (size_t)T * NB * CAP * 12;
    size_t cnt_off     = ent_off + ent_bytes;
    size_t cnt_bytes   = (size_t)T * NB * 4;
    size_t need        = cnt_off + cnt_bytes;

    float* u_lo = (float*)d_ws;
    unsigned* entries = (unsigned*)((char*)d_ws + ent_off);
    unsigned* counts  = (unsigned*)((char*)d_ws + cnt_off);

    // lambda = 2*chunk/T must stay <= 25 for CAP=38 (+2.7 sigma)
    bool fast = (ws_size >= need && T <= 256 && 2 * chunk <= 25 * T + T / 8);

    int tb = 256;
    unary_enhance_kernel<<<(n_nodes + tb - 1) / tb, tb, 0, stream>>>(
        unary, ucw, out_u, u_lo, n_nodes);

    if (fast) {
        bin_edges_kernel<<<NB, BT, 0, stream>>>(
            binary, bcw, index1, index2, u_lo, out_b,
            counts, entries, out_u, n_edges, T, chunk);
        tile_acc_kernel<<<T, BTA, 0, stream>>>(
            counts, entries, out_u, n_nodes);
    } else {
        edge_enhance_kernel<<<(n_edges + tb - 1) / tb, tb, 0, stream>>>(
            binary, bcw, index1, index2, u_lo, out_u, out_b, n_edges);
    }
}

// Round 17
// 176.811 us; speedup vs baseline: 1.0432x; 1.0231x over previous
//
#include <hip/hip_runtime.h>
#include <math.h>

// RelationalKENN R23: R22 + fp16 u_lo (halve the L2-contended gather table).
//
// Ledger:
//  R10 global u64 atomics ✗. R11/R16 NB>512 ✗✗ (L2-capacity). R12 fusion ✗.
//  R13b nt split (loads ✓ / scatter-store ✗). R14 ✓ 190.3. R15 ∅.
//  R17 TILE_N=200 wash. R18 12B entries ✓ 185.4. R19 replicated acc ∅.
//  R20 ILP-4 ✓ 183.0. R21 single-pass bin ✓ (bin 80.5) / acc sweep ✗.
//  R22 acc group-skip ✓ 180.9 BEST.
//  Accounting: ~40-45us of dur_us is fixed harness overhead (kernel sums
//  consistently ~40 below total since R9). acc at ~43us LDS-atomic floor.
//  R23: bin FETCH 71 vs 42 ideal => ~29MB u_lo re-fetch (3.2MB fp32 table
//      loses L2 residency to the entries write frontier). fp16 u_lo: 1.6MB
//      table, one dwordx4 per gather side (was two), half the re-fetch.
//      Precision: ~5e-4 input rounding << 1/512 entry quantization << 0.125.
//      Predict: bin FETCH ->52-58MB, dur ->73-78, total ->174-178.
//      Falsifier: bin >=80 => all components at structural floor, declare
//      converged.

#define NU 16
#define NC 8
#define TILE_N 400u
#define NB 512        // bin-pass blocks
#define BT 512        // bin-pass block size
#define ACC_ST 400
#define BTA 1024      // tile_acc block size
#define CAP 38        // per-(block,bin) entry capacity (lambda=25 + 2.7sigma)

typedef float    f32x4 __attribute__((ext_vector_type(4)));
typedef unsigned u32x4 __attribute__((ext_vector_type(4)));
typedef _Float16 f16x8 __attribute__((ext_vector_type(8)));   // 16B

__device__ __forceinline__ int q10(float x) {
    int q = __float2int_rn(x * 512.0f);
    q = q < -511 ? -511 : (q > 511 ? 511 : q);
    return q & 0x3FF;
}
__device__ __forceinline__ int sx10(unsigned w, int sh) {
    return ((int)(w << (22 - sh))) >> 22;
}
__device__ __forceinline__ unsigned long long pk4(int a0, int a1, int a2, int a3) {
    return (unsigned long long)(long long)a0 +
           ((unsigned long long)(long long)a1 << 16) +
           ((unsigned long long)(long long)a2 << 32) +
           ((unsigned long long)(unsigned short)a3 << 48);
}

__global__ void unary_enhance_kernel(const float* __restrict__ unary,
                                     const float* __restrict__ ucw,
                                     float* __restrict__ out_u,    // [n_nodes*16]
                                     _Float16* __restrict__ u_lo,  // [n_nodes*8] fp16
                                     int n_nodes) {
    int n = blockIdx.x * blockDim.x + threadIdx.x;
    if (n >= n_nodes) return;

    float x[NU];
    const float4* src = (const float4*)(unary + (size_t)n * NU);
#pragma unroll
    for (int j = 0; j < 4; ++j) {
        float4 v = src[j];
        x[4*j+0] = v.x; x[4*j+1] = v.y; x[4*j+2] = v.z; x[4*j+3] = v.w;
    }
    float dlt[NU];
#pragma unroll
    for (int j = 0; j < NU; ++j) dlt[j] = 0.0f;
#pragma unroll
    for (int i = 0; i < NC; ++i) {
        float w = ucw[i];
        float a = -x[i], b = x[i+1], c = x[i+2];
        float m = fmaxf(a, fmaxf(b, c));
        float e0 = __expf(a - m);
        float e1 = __expf(b - m);
        float e2 = __expf(c - m);
        float inv = 1.0f / (e0 + e1 + e2);
        dlt[i]   -= w * e0 * inv;
        dlt[i+1] += w * e1 * inv;
        dlt[i+2] += w * e2 * inv;
    }
    float u[NU];
#pragma unroll
    for (int j = 0; j < NU; ++j) u[j] = x[j] + dlt[j];

    float4* dst = (float4*)(out_u + (size_t)n * NU);
#pragma unroll
    for (int j = 0; j < 4; ++j) {
        float4 v; v.x = u[4*j+0]; v.y = u[4*j+1]; v.z = u[4*j+2]; v.w = u[4*j+3];
        dst[j] = v;
    }
    // u_lo fp16: 16B/node — half the L2 footprint, one dwordx4 per gather.
    f16x8 h;
#pragma unroll
    for (int j = 0; j < 8; ++j) h[j] = (_Float16)u[j];
    *((f16x8*)(u_lo + (size_t)n * 8)) = h;
}

// Softmax + out_b + 2 scatter entries (12B) for one edge; slot comes
// directly from the LDS histogram atomic (single-pass scheme).
__device__ __forceinline__ void edge_body(int e, int i1, int i2, f32x4 bv,
                                          f16x8 h1, f16x8 h2,
                                          const float* w,
                                          float* __restrict__ out_b,
                                          unsigned* hist,
                                          unsigned* __restrict__ eblk, // entries + blk*CAP*3
                                          float* __restrict__ out_u) {
    float b[4] = {bv.x, bv.y, bv.z, bv.w};
    float u1[8], u2[8];
#pragma unroll
    for (int j = 0; j < 8; ++j) { u1[j] = (float)h1[j]; u2[j] = (float)h2[j]; }

    float d1[8], d2[8], dbp[4] = {0.f,0.f,0.f,0.f};
#pragma unroll
    for (int i = 0; i < NC; ++i) {
        float a = -u1[i], bb = b[i & 3], c = u2[i];
        float m = fmaxf(a, fmaxf(bb, c));
        float e0x = __expf(a - m);
        float e1x = __expf(bb - m);
        float e2x = __expf(c - m);
        float inv = 1.0f / (e0x + e1x + e2x);
        d1[i] = -w[i] * e0x * inv;
        d2[i] =  w[i] * e2x * inv;
        dbp[i & 3] += w[i] * e1x * inv;
    }
    f32x4 ob;
    ob.x = b[0] + dbp[0];
    ob.y = b[1] + dbp[1];
    ob.z = b[2] + dbp[2];
    ob.w = b[3] + dbp[3];
    __builtin_nontemporal_store(ob, ((f32x4*)out_b) + e);

    unsigned t1 = (unsigned)i1 / TILE_N;
    unsigned id1 = (unsigned)i1 - t1 * TILE_N;
    unsigned slot1 = atomicAdd(&hist[t1], 1u);
    if (slot1 < (unsigned)CAP) {
        unsigned* ep = eblk + ((size_t)t1 * (NB * CAP) + slot1) * 3;
        ep[0] = (unsigned)q10(d1[0]) | ((unsigned)q10(d1[1]) << 10) | ((unsigned)q10(d1[2]) << 20);
        ep[1] = (unsigned)q10(d1[3]) | ((unsigned)q10(d1[4]) << 10) | ((unsigned)q10(d1[5]) << 20);
        ep[2] = (unsigned)q10(d1[6]) | ((unsigned)q10(d1[7]) << 10) | (id1 << 20);
    } else {
        float* r = out_u + (size_t)i1 * NU;
#pragma unroll
        for (int i = 0; i < NC; ++i) atomicAdd(r + i, d1[i]);
    }

    unsigned t2 = (unsigned)i2 / TILE_N;
    unsigned id2 = (unsigned)i2 - t2 * TILE_N;
    unsigned slot2 = atomicAdd(&hist[t2], 1u);
    if (slot2 < (unsigned)CAP) {
        unsigned* ep = eblk + ((size_t)t2 * (NB * CAP) + slot2) * 3;
        ep[0] = (unsigned)q10(d2[0]) | ((unsigned)q10(d2[1]) << 10) | ((unsigned)q10(d2[2]) << 20);
        ep[1] = (unsigned)q10(d2[3]) | ((unsigned)q10(d2[4]) << 10) | ((unsigned)q10(d2[5]) << 20);
        ep[2] = (unsigned)q10(d2[6]) | ((unsigned)q10(d2[7]) << 10) | (id2 << 20);
    } else {
        float* r = out_u + (size_t)i2 * NU;
#pragma unroll
        for (int i = 0; i < NC; ++i) atomicAdd(r + i, d2[i]);
    }
}

__global__ __launch_bounds__(BT, 4)
void bin_edges_kernel(const float* __restrict__ binary,
                      const float* __restrict__ bcw,
                      const int* __restrict__ index1,
                      const int* __restrict__ index2,
                      const _Float16* __restrict__ u_lo,
                      float* __restrict__ out_b,       // [n_edges*4]
                      unsigned* __restrict__ counts,   // [T*NB]
                      unsigned* __restrict__ entries,  // [T*NB*CAP*3 u32]
                      float* __restrict__ out_u,       // overflow path only
                      int n_edges, int T, int chunk) {
    __shared__ unsigned hist[256];
    int tid = threadIdx.x;
    for (int t = tid; t < T; t += BT) hist[t] = 0u;
    __syncthreads();

    int e0 = blockIdx.x * chunk;
    int e1 = e0 + chunk; if (e1 > n_edges) e1 = n_edges;

    unsigned* eblk = entries + (size_t)blockIdx.x * CAP * 3;

    float w[NC];
#pragma unroll
    for (int i = 0; i < NC; ++i) w[i] = bcw[i];

    // single pass, 4x unrolled — four independent gather chains in flight.
    int eA = e0 + tid;
    for (; eA + 3 * BT < e1; eA += 4 * BT) {
        int eB = eA + BT, eC = eA + 2 * BT, eD = eA + 3 * BT;
        int i1A = __builtin_nontemporal_load(index1 + eA);
        int i2A = __builtin_nontemporal_load(index2 + eA);
        int i1B = __builtin_nontemporal_load(index1 + eB);
        int i2B = __builtin_nontemporal_load(index2 + eB);
        int i1C = __builtin_nontemporal_load(index1 + eC);
        int i2C = __builtin_nontemporal_load(index2 + eC);
        int i1D = __builtin_nontemporal_load(index1 + eD);
        int i2D = __builtin_nontemporal_load(index2 + eD);

        f32x4 bvA = __builtin_nontemporal_load(((const f32x4*)binary) + eA);
        f32x4 bvB = __builtin_nontemporal_load(((const f32x4*)binary) + eB);
        f32x4 bvC = __builtin_nontemporal_load(((const f32x4*)binary) + eC);
        f32x4 bvD = __builtin_nontemporal_load(((const f32x4*)binary) + eD);

        f16x8 h1A = *((const f16x8*)(u_lo + (size_t)i1A * 8));
        f16x8 h2A = *((const f16x8*)(u_lo + (size_t)i2A * 8));
        f16x8 h1B = *((const f16x8*)(u_lo + (size_t)i1B * 8));
        f16x8 h2B = *((const f16x8*)(u_lo + (size_t)i2B * 8));
        f16x8 h1C = *((const f16x8*)(u_lo + (size_t)i1C * 8));
        f16x8 h2C = *((const f16x8*)(u_lo + (size_t)i2C * 8));
        f16x8 h1D = *((const f16x8*)(u_lo + (size_t)i1D * 8));
        f16x8 h2D = *((const f16x8*)(u_lo + (size_t)i2D * 8));

        edge_body(eA, i1A, i2A, bvA, h1A, h2A, w, out_b, hist, eblk, out_u);
        edge_body(eB, i1B, i2B, bvB, h1B, h2B, w, out_b, hist, eblk, out_u);
        edge_body(eC, i1C, i2C, bvC, h1C, h2C, w, out_b, hist, eblk, out_u);
        edge_body(eD, i1D, i2D, bvD, h1D, h2D, w, out_b, hist, eblk, out_u);
    }
    for (; eA < e1; eA += BT) {
        int i1A = __builtin_nontemporal_load(index1 + eA);
        int i2A = __builtin_nontemporal_load(index2 + eA);
        f32x4 bvA = __builtin_nontemporal_load(((const f32x4*)binary) + eA);
        f16x8 h1A = *((const f16x8*)(u_lo + (size_t)i1A * 8));
        f16x8 h2A = *((const f16x8*)(u_lo + (size_t)i2A * 8));
        edge_body(eA, i1A, i2A, bvA, h1A, h2A, w, out_b, hist, eblk, out_u);
    }
    __syncthreads();

    // publish per-(block,bin) counts (acc clamps to CAP)
    for (int t = tid; t < T; t += BT) counts[(size_t)t * NB + blockIdx.x] = hist[t];
}

// Accumulate pass: sweep the tile's static region; SKIP provably-all-invalid
// 4-entry groups before loading (slots fill from 0 in each cell).
__global__ __launch_bounds__(BTA)
void tile_acc_kernel(const unsigned* __restrict__ counts,
                     const unsigned* __restrict__ entries,
                     float* __restrict__ out_u,
                     int n_nodes) {
    __shared__ unsigned long long acc[2 * ACC_ST];
    __shared__ unsigned cnt[NB];
    int t = blockIdx.x;
    int tid = threadIdx.x;
    for (int i = tid; i < 2 * ACC_ST; i += BTA) acc[i] = 0ull;
    for (int i = tid; i < NB; i += BTA) {
        unsigned c = counts[(size_t)t * NB + i];
        cnt[i] = c > (unsigned)CAP ? (unsigned)CAP : c;
    }
    __syncthreads();

    const unsigned total = NB * CAP;                       // 19456, %4 == 0
    const unsigned* base = entries + (size_t)t * NB * CAP * 3;

    for (unsigned j4 = (unsigned)tid * 4; j4 < total; j4 += BTA * 4) {
        unsigned b0 = j4 / (unsigned)CAP;
        unsigned s0 = j4 - b0 * (unsigned)CAP;
        unsigned b1 = (j4 + 3u) / (unsigned)CAP;
        bool anyvalid = (s0 < cnt[b0]) || (b1 != b0 && cnt[b1] > 0u);
        if (!anyvalid) continue;

        const u32x4* p = (const u32x4*)(base + (size_t)j4 * 3);
        u32x4 q0 = __builtin_nontemporal_load(p + 0);
        u32x4 q1 = __builtin_nontemporal_load(p + 1);
        u32x4 q2 = __builtin_nontemporal_load(p + 2);
        unsigned d[12] = {q0.x, q0.y, q0.z, q0.w,
                          q1.x, q1.y, q1.z, q1.w,
                          q2.x, q2.y, q2.z, q2.w};
#pragma unroll
        for (int k = 0; k < 4; ++k) {
            unsigned j = j4 + (unsigned)k;
            unsigned blk = j / (unsigned)CAP;              // compile-time divisor
            unsigned slot = j - blk * (unsigned)CAP;
            if (slot >= cnt[blk]) continue;
            unsigned wx = d[3*k], wy = d[3*k+1], wz = d[3*k+2];
            unsigned id = wz >> 20;
            unsigned long long lo = pk4(sx10(wx, 0), sx10(wx, 10), sx10(wx, 20), sx10(wy, 0));
            unsigned long long hi = pk4(sx10(wy, 10), sx10(wy, 20), sx10(wz, 0), sx10(wz, 10));
            atomicAdd(&acc[id], lo);
            atomicAdd(&acc[ACC_ST + id], hi);
        }
    }
    __syncthreads();

    const float INV = 1.0f / 512.0f;
    int nbase = t * (int)TILE_N;
    for (int l = tid; l < (int)TILE_N; l += BTA) {
        int n = nbase + l;
        if (n >= n_nodes) continue;
        float col[8];
#pragma unroll
        for (int wd = 0; wd < 2; ++wd) {
            unsigned long long S = acc[wd*ACC_ST + l];
#pragma unroll
            for (int f = 0; f < 4; ++f) {
                short s = (short)(S & 0xFFFFull);
                col[wd*4 + f] = (float)s * INV;
                S = (S - (unsigned long long)(long long)s) >> 16;
            }
        }
        float4* row = (float4*)(out_u + (size_t)n * NU);
        float4 r0 = row[0], r1 = row[1];
        r0.x += col[0]; r0.y += col[1]; r0.z += col[2]; r0.w += col[3];
        r1.x += col[4]; r1.y += col[5]; r1.z += col[6]; r1.w += col[7];
        row[0] = r0; row[1] = r1;
    }
}

// Fallback (R1): device-scope atomics, needs only u_lo in ws.
__global__ void edge_enhance_kernel(const float* __restrict__ binary,
                                    const float* __restrict__ bcw,
                                    const int* __restrict__ index1,
                                    const int* __restrict__ index2,
                                    const _Float16* __restrict__ u_lo,
                                    float* __restrict__ out_u,
                                    float* __restrict__ out_b,
                                    int n_edges) {
    int e = blockIdx.x * blockDim.x + threadIdx.x;
    if (e >= n_edges) return;

    int i1 = index1[e];
    int i2 = index2[e];
    float4 bv = ((const float4*)binary)[e];
    float b[4] = {bv.x, bv.y, bv.z, bv.w};

    f16x8 h1 = *((const f16x8*)(u_lo + (size_t)i1 * 8));
    f16x8 h2 = *((const f16x8*)(u_lo + (size_t)i2 * 8));
    float u1[8], u2[8];
#pragma unroll
    for (int j = 0; j < 8; ++j) { u1[j] = (float)h1[j]; u2[j] = (float)h2[j]; }

    float d1[8], d2[8], dbp[4] = {0.f,0.f,0.f,0.f};
#pragma unroll
    for (int i = 0; i < NC; ++i) {
        float w = bcw[i];
        float a = -u1[i], bb = b[i & 3], c = u2[i];
        float m = fmaxf(a, fmaxf(bb, c));
        float e0 = __expf(a - m);
        float e1 = __expf(bb - m);
        float e2 = __expf(c - m);
        float inv = 1.0f / (e0 + e1 + e2);
        d1[i] = -w * e0 * inv;
        d2[i] =  w * e2 * inv;
        dbp[i & 3] += w * e1 * inv;
    }
    float* r1 = out_u + (size_t)i1 * NU;
#pragma unroll
    for (int i = 0; i < NC; ++i) atomicAdd(r1 + i, d1[i]);
    float* r2 = out_u + (size_t)i2 * NU;
#pragma unroll
    for (int i = 0; i < NC; ++i) atomicAdd(r2 + i, d2[i]);

    float4 ob;
    ob.x = b[0] + dbp[0];
    ob.y = b[1] + dbp[1];
    ob.z = b[2] + dbp[2];
    ob.w = b[3] + dbp[3];
    ((float4*)out_b)[e] = ob;
}

extern "C" void kernel_launch(void* const* d_in, const int* in_sizes, int n_in,
                              void* d_out, int out_size, void* d_ws, size_t ws_size,
                              hipStream_t stream) {
    const float* unary  = (const float*)d_in[0];
    const float* binary = (const float*)d_in[1];
    const float* ucw    = (const float*)d_in[2];
    const float* bcw    = (const float*)d_in[3];
    const int*   index1 = (const int*)d_in[4];
    const int*   index2 = (const int*)d_in[5];

    int n_nodes = in_sizes[0] / NU;
    int n_edges = in_sizes[4];

    float* out_u = (float*)d_out;
    float* out_b = out_u + (size_t)n_nodes * NU;

    int T = (int)(((unsigned)n_nodes + TILE_N - 1) / TILE_N);   // 250
    int chunk = (n_edges + NB - 1) / NB;                        // 3125

    // ws layout: u_lo [n_nodes*8 f16] | entries [T*NB*CAP*3 u32] | counts [T*NB u32]
    size_t u_lo_bytes  = (size_t)n_nodes * 8 * sizeof(_Float16);
    size_t ent_off     = (u_lo_bytes + 63) & ~(size_t)63;
    size_t ent_bytes   = (size_t)T * NB * CAP * 12;
    size_t cnt_off     = ent_off + ent_bytes;
    size_t cnt_bytes   = (size_t)T * NB * 4;
    size_t need        = cnt_off + cnt_bytes;

    _Float16* u_lo = (_Float16*)d_ws;
    unsigned* entries = (unsigned*)((char*)d_ws + ent_off);
    unsigned* counts  = (unsigned*)((char*)d_ws + cnt_off);

    // lambda = 2*chunk/T must stay <= 25 for CAP=38 (+2.7 sigma)
    bool fast = (ws_size >= need && T <= 256 && 2 * chunk <= 25 * T + T / 8);

    int tb = 256;
    unary_enhance_kernel<<<(n_nodes + tb - 1) / tb, tb, 0, stream>>>(
        unary, ucw, out_u, u_lo, n_nodes);

    if (fast) {
        bin_edges_kernel<<<NB, BT, 0, stream>>>(
            binary, bcw, index1, index2, u_lo, out_b,
            counts, entries, out_u, n_edges, T, chunk);
        tile_acc_kernel<<<T, BTA, 0, stream>>>(
            counts, entries, out_u, n_nodes);
    } else {
        edge_enhance_kernel<<<(n_edges + tb - 1) / tb, tb, 0, stream>>>(
            binary, bcw, index1, index2, u_lo, out_u, out_b, n_edges);
    }
}

// Round 18
// 169.227 us; speedup vs baseline: 1.0899x; 1.0448x over previous
//
#include <hip/hip_runtime.h>
#include <math.h>

// RelationalKENN R24: R23 + NB 512->256, BT 512->1024 (halve the scattered
// entries write frontier; double cell fill -> less partial-line RFO).
//
// Ledger:
//  R10 global u64 atomics ✗. R11/R16 NB>512 ✗✗ (frontier grows). R12 fusion ✗.
//  R13b nt split (loads ✓ / scatter-store ✗). R14 ✓ 190.3. R15 ∅.
//  R17 TILE_N=200 wash. R18 12B entries ✓ 185.4. R19 replicated acc ∅.
//  R20 ILP-4 ✓ 183.0. R21 single-pass bin ✓. R22 acc group-skip ✓ 180.9.
//  R23 fp16 u_lo ✓ 176.8 BEST — bin FETCH 71->33MB (u_lo re-fetch gone).
//  R24: bin WRITE 120 vs ~71 ideal = ~50MB partial-line RFO on 12B entry
//      scatter (456B cells, lambda 25/38 filled). Fewer+bigger blocks:
//      frontier 512->256 cells-sets (0.5MB/XCD), cells 600B-filled of 840B
//      (CAP=70 = lambda50 + 2.8sigma), per-entry boundary waste halves.
//      Opposite direction from refuted NB>512. ws 55.6MB (<62.9 proven).
//      Predict: WRITE ->100-108MB, bin ->66-70, total ->171-175.
//      Falsifier: bin >=72 => all scatter hypotheses exonerated, converged.

#define NU 16
#define NC 8
#define TILE_N 400u
#define NB 256        // bin-pass blocks
#define BT 1024       // bin-pass block size
#define ACC_ST 400
#define BTA 1024      // tile_acc block size
#define CAP 70        // per-(block,bin) entry capacity (lambda=50 + 2.8sigma)

typedef float    f32x4 __attribute__((ext_vector_type(4)));
typedef unsigned u32x4 __attribute__((ext_vector_type(4)));
typedef _Float16 f16x8 __attribute__((ext_vector_type(8)));   // 16B

__device__ __forceinline__ int q10(float x) {
    int q = __float2int_rn(x * 512.0f);
    q = q < -511 ? -511 : (q > 511 ? 511 : q);
    return q & 0x3FF;
}
__device__ __forceinline__ int sx10(unsigned w, int sh) {
    return ((int)(w << (22 - sh))) >> 22;
}
__device__ __forceinline__ unsigned long long pk4(int a0, int a1, int a2, int a3) {
    return (unsigned long long)(long long)a0 +
           ((unsigned long long)(long long)a1 << 16) +
           ((unsigned long long)(long long)a2 << 32) +
           ((unsigned long long)(unsigned short)a3 << 48);
}

__global__ void unary_enhance_kernel(const float* __restrict__ unary,
                                     const float* __restrict__ ucw,
                                     float* __restrict__ out_u,    // [n_nodes*16]
                                     _Float16* __restrict__ u_lo,  // [n_nodes*8] fp16
                                     int n_nodes) {
    int n = blockIdx.x * blockDim.x + threadIdx.x;
    if (n >= n_nodes) return;

    float x[NU];
    const float4* src = (const float4*)(unary + (size_t)n * NU);
#pragma unroll
    for (int j = 0; j < 4; ++j) {
        float4 v = src[j];
        x[4*j+0] = v.x; x[4*j+1] = v.y; x[4*j+2] = v.z; x[4*j+3] = v.w;
    }
    float dlt[NU];
#pragma unroll
    for (int j = 0; j < NU; ++j) dlt[j] = 0.0f;
#pragma unroll
    for (int i = 0; i < NC; ++i) {
        float w = ucw[i];
        float a = -x[i], b = x[i+1], c = x[i+2];
        float m = fmaxf(a, fmaxf(b, c));
        float e0 = __expf(a - m);
        float e1 = __expf(b - m);
        float e2 = __expf(c - m);
        float inv = 1.0f / (e0 + e1 + e2);
        dlt[i]   -= w * e0 * inv;
        dlt[i+1] += w * e1 * inv;
        dlt[i+2] += w * e2 * inv;
    }
    float u[NU];
#pragma unroll
    for (int j = 0; j < NU; ++j) u[j] = x[j] + dlt[j];

    float4* dst = (float4*)(out_u + (size_t)n * NU);
#pragma unroll
    for (int j = 0; j < 4; ++j) {
        float4 v; v.x = u[4*j+0]; v.y = u[4*j+1]; v.z = u[4*j+2]; v.w = u[4*j+3];
        dst[j] = v;
    }
    // u_lo fp16: 16B/node — half the L2 footprint, one dwordx4 per gather.
    f16x8 h;
#pragma unroll
    for (int j = 0; j < 8; ++j) h[j] = (_Float16)u[j];
    *((f16x8*)(u_lo + (size_t)n * 8)) = h;
}

// Softmax + out_b + 2 scatter entries (12B) for one edge; slot comes
// directly from the LDS histogram atomic (single-pass scheme).
__device__ __forceinline__ void edge_body(int e, int i1, int i2, f32x4 bv,
                                          f16x8 h1, f16x8 h2,
                                          const float* w,
                                          float* __restrict__ out_b,
                                          unsigned* hist,
                                          unsigned* __restrict__ eblk, // entries + blk*CAP*3
                                          float* __restrict__ out_u) {
    float b[4] = {bv.x, bv.y, bv.z, bv.w};
    float u1[8], u2[8];
#pragma unroll
    for (int j = 0; j < 8; ++j) { u1[j] = (float)h1[j]; u2[j] = (float)h2[j]; }

    float d1[8], d2[8], dbp[4] = {0.f,0.f,0.f,0.f};
#pragma unroll
    for (int i = 0; i < NC; ++i) {
        float a = -u1[i], bb = b[i & 3], c = u2[i];
        float m = fmaxf(a, fmaxf(bb, c));
        float e0x = __expf(a - m);
        float e1x = __expf(bb - m);
        float e2x = __expf(c - m);
        float inv = 1.0f / (e0x + e1x + e2x);
        d1[i] = -w[i] * e0x * inv;
        d2[i] =  w[i] * e2x * inv;
        dbp[i & 3] += w[i] * e1x * inv;
    }
    f32x4 ob;
    ob.x = b[0] + dbp[0];
    ob.y = b[1] + dbp[1];
    ob.z = b[2] + dbp[2];
    ob.w = b[3] + dbp[3];
    __builtin_nontemporal_store(ob, ((f32x4*)out_b) + e);

    unsigned t1 = (unsigned)i1 / TILE_N;
    unsigned id1 = (unsigned)i1 - t1 * TILE_N;
    unsigned slot1 = atomicAdd(&hist[t1], 1u);
    if (slot1 < (unsigned)CAP) {
        unsigned* ep = eblk + ((size_t)t1 * (NB * CAP) + slot1) * 3;
        ep[0] = (unsigned)q10(d1[0]) | ((unsigned)q10(d1[1]) << 10) | ((unsigned)q10(d1[2]) << 20);
        ep[1] = (unsigned)q10(d1[3]) | ((unsigned)q10(d1[4]) << 10) | ((unsigned)q10(d1[5]) << 20);
        ep[2] = (unsigned)q10(d1[6]) | ((unsigned)q10(d1[7]) << 10) | (id1 << 20);
    } else {
        float* r = out_u + (size_t)i1 * NU;
#pragma unroll
        for (int i = 0; i < NC; ++i) atomicAdd(r + i, d1[i]);
    }

    unsigned t2 = (unsigned)i2 / TILE_N;
    unsigned id2 = (unsigned)i2 - t2 * TILE_N;
    unsigned slot2 = atomicAdd(&hist[t2], 1u);
    if (slot2 < (unsigned)CAP) {
        unsigned* ep = eblk + ((size_t)t2 * (NB * CAP) + slot2) * 3;
        ep[0] = (unsigned)q10(d2[0]) | ((unsigned)q10(d2[1]) << 10) | ((unsigned)q10(d2[2]) << 20);
        ep[1] = (unsigned)q10(d2[3]) | ((unsigned)q10(d2[4]) << 10) | ((unsigned)q10(d2[5]) << 20);
        ep[2] = (unsigned)q10(d2[6]) | ((unsigned)q10(d2[7]) << 10) | (id2 << 20);
    } else {
        float* r = out_u + (size_t)i2 * NU;
#pragma unroll
        for (int i = 0; i < NC; ++i) atomicAdd(r + i, d2[i]);
    }
}

__global__ __launch_bounds__(BT, 2)
void bin_edges_kernel(const float* __restrict__ binary,
                      const float* __restrict__ bcw,
                      const int* __restrict__ index1,
                      const int* __restrict__ index2,
                      const _Float16* __restrict__ u_lo,
                      float* __restrict__ out_b,       // [n_edges*4]
                      unsigned* __restrict__ counts,   // [T*NB]
                      unsigned* __restrict__ entries,  // [T*NB*CAP*3 u32]
                      float* __restrict__ out_u,       // overflow path only
                      int n_edges, int T, int chunk) {
    __shared__ unsigned hist[256];
    int tid = threadIdx.x;
    for (int t = tid; t < T; t += BT) hist[t] = 0u;
    __syncthreads();

    int e0 = blockIdx.x * chunk;
    int e1 = e0 + chunk; if (e1 > n_edges) e1 = n_edges;

    unsigned* eblk = entries + (size_t)blockIdx.x * CAP * 3;

    float w[NC];
#pragma unroll
    for (int i = 0; i < NC; ++i) w[i] = bcw[i];

    // single pass, 4x unrolled — four independent gather chains in flight.
    int eA = e0 + tid;
    for (; eA + 3 * BT < e1; eA += 4 * BT) {
        int eB = eA + BT, eC = eA + 2 * BT, eD = eA + 3 * BT;
        int i1A = __builtin_nontemporal_load(index1 + eA);
        int i2A = __builtin_nontemporal_load(index2 + eA);
        int i1B = __builtin_nontemporal_load(index1 + eB);
        int i2B = __builtin_nontemporal_load(index2 + eB);
        int i1C = __builtin_nontemporal_load(index1 + eC);
        int i2C = __builtin_nontemporal_load(index2 + eC);
        int i1D = __builtin_nontemporal_load(index1 + eD);
        int i2D = __builtin_nontemporal_load(index2 + eD);

        f32x4 bvA = __builtin_nontemporal_load(((const f32x4*)binary) + eA);
        f32x4 bvB = __builtin_nontemporal_load(((const f32x4*)binary) + eB);
        f32x4 bvC = __builtin_nontemporal_load(((const f32x4*)binary) + eC);
        f32x4 bvD = __builtin_nontemporal_load(((const f32x4*)binary) + eD);

        f16x8 h1A = *((const f16x8*)(u_lo + (size_t)i1A * 8));
        f16x8 h2A = *((const f16x8*)(u_lo + (size_t)i2A * 8));
        f16x8 h1B = *((const f16x8*)(u_lo + (size_t)i1B * 8));
        f16x8 h2B = *((const f16x8*)(u_lo + (size_t)i2B * 8));
        f16x8 h1C = *((const f16x8*)(u_lo + (size_t)i1C * 8));
        f16x8 h2C = *((const f16x8*)(u_lo + (size_t)i2C * 8));
        f16x8 h1D = *((const f16x8*)(u_lo + (size_t)i1D * 8));
        f16x8 h2D = *((const f16x8*)(u_lo + (size_t)i2D * 8));

        edge_body(eA, i1A, i2A, bvA, h1A, h2A, w, out_b, hist, eblk, out_u);
        edge_body(eB, i1B, i2B, bvB, h1B, h2B, w, out_b, hist, eblk, out_u);
        edge_body(eC, i1C, i2C, bvC, h1C, h2C, w, out_b, hist, eblk, out_u);
        edge_body(eD, i1D, i2D, bvD, h1D, h2D, w, out_b, hist, eblk, out_u);
    }
    for (; eA < e1; eA += BT) {
        int i1A = __builtin_nontemporal_load(index1 + eA);
        int i2A = __builtin_nontemporal_load(index2 + eA);
        f32x4 bvA = __builtin_nontemporal_load(((const f32x4*)binary) + eA);
        f16x8 h1A = *((const f16x8*)(u_lo + (size_t)i1A * 8));
        f16x8 h2A = *((const f16x8*)(u_lo + (size_t)i2A * 8));
        edge_body(eA, i1A, i2A, bvA, h1A, h2A, w, out_b, hist, eblk, out_u);
    }
    __syncthreads();

    // publish per-(block,bin) counts (acc clamps to CAP)
    for (int t = tid; t < T; t += BT) counts[(size_t)t * NB + blockIdx.x] = hist[t];
}

// Accumulate pass: sweep the tile's static region; SKIP provably-all-invalid
// 4-entry groups before loading (slots fill from 0 in each cell).
__global__ __launch_bounds__(BTA)
void tile_acc_kernel(const unsigned* __restrict__ counts,
                     const unsigned* __restrict__ entries,
                     float* __restrict__ out_u,
                     int n_nodes) {
    __shared__ unsigned long long acc[2 * ACC_ST];
    __shared__ unsigned cnt[NB];
    int t = blockIdx.x;
    int tid = threadIdx.x;
    for (int i = tid; i < 2 * ACC_ST; i += BTA) acc[i] = 0ull;
    for (int i = tid; i < NB; i += BTA) {
        unsigned c = counts[(size_t)t * NB + i];
        cnt[i] = c > (unsigned)CAP ? (unsigned)CAP : c;
    }
    __syncthreads();

    const unsigned total = NB * CAP;                       // 17920, %4 == 0
    const unsigned* base = entries + (size_t)t * NB * CAP * 3;

    for (unsigned j4 = (unsigned)tid * 4; j4 < total; j4 += BTA * 4) {
        unsigned b0 = j4 / (unsigned)CAP;
        unsigned s0 = j4 - b0 * (unsigned)CAP;
        unsigned b1 = (j4 + 3u) / (unsigned)CAP;
        bool anyvalid = (s0 < cnt[b0]) || (b1 != b0 && cnt[b1] > 0u);
        if (!anyvalid) continue;

        const u32x4* p = (const u32x4*)(base + (size_t)j4 * 3);
        u32x4 q0 = __builtin_nontemporal_load(p + 0);
        u32x4 q1 = __builtin_nontemporal_load(p + 1);
        u32x4 q2 = __builtin_nontemporal_load(p + 2);
        unsigned d[12] = {q0.x, q0.y, q0.z, q0.w,
                          q1.x, q1.y, q1.z, q1.w,
                          q2.x, q2.y, q2.z, q2.w};
#pragma unroll
        for (int k = 0; k < 4; ++k) {
            unsigned j = j4 + (unsigned)k;
            unsigned blk = j / (unsigned)CAP;              // compile-time divisor
            unsigned slot = j - blk * (unsigned)CAP;
            if (slot >= cnt[blk]) continue;
            unsigned wx = d[3*k], wy = d[3*k+1], wz = d[3*k+2];
            unsigned id = wz >> 20;
            unsigned long long lo = pk4(sx10(wx, 0), sx10(wx, 10), sx10(wx, 20), sx10(wy, 0));
            unsigned long long hi = pk4(sx10(wy, 10), sx10(wy, 20), sx10(wz, 0), sx10(wz, 10));
            atomicAdd(&acc[id], lo);
            atomicAdd(&acc[ACC_ST + id], hi);
        }
    }
    __syncthreads();

    const float INV = 1.0f / 512.0f;
    int nbase = t * (int)TILE_N;
    for (int l = tid; l < (int)TILE_N; l += BTA) {
        int n = nbase + l;
        if (n >= n_nodes) continue;
        float col[8];
#pragma unroll
        for (int wd = 0; wd < 2; ++wd) {
            unsigned long long S = acc[wd*ACC_ST + l];
#pragma unroll
            for (int f = 0; f < 4; ++f) {
                short s = (short)(S & 0xFFFFull);
                col[wd*4 + f] = (float)s * INV;
                S = (S - (unsigned long long)(long long)s) >> 16;
            }
        }
        float4* row = (float4*)(out_u + (size_t)n * NU);
        float4 r0 = row[0], r1 = row[1];
        r0.x += col[0]; r0.y += col[1]; r0.z += col[2]; r0.w += col[3];
        r1.x += col[4]; r1.y += col[5]; r1.z += col[6]; r1.w += col[7];
        row[0] = r0; row[1] = r1;
    }
}

// Fallback (R1): device-scope atomics, needs only u_lo in ws.
__global__ void edge_enhance_kernel(const float* __restrict__ binary,
                                    const float* __restrict__ bcw,
                                    const int* __restrict__ index1,
                                    const int* __restrict__ index2,
                                    const _Float16* __restrict__ u_lo,
                                    float* __restrict__ out_u,
                                    float* __restrict__ out_b,
                                    int n_edges) {
    int e = blockIdx.x * blockDim.x + threadIdx.x;
    if (e >= n_edges) return;

    int i1 = index1[e];
    int i2 = index2[e];
    float4 bv = ((const float4*)binary)[e];
    float b[4] = {bv.x, bv.y, bv.z, bv.w};

    f16x8 h1 = *((const f16x8*)(u_lo + (size_t)i1 * 8));
    f16x8 h2 = *((const f16x8*)(u_lo + (size_t)i2 * 8));
    float u1[8], u2[8];
#pragma unroll
    for (int j = 0; j < 8; ++j) { u1[j] = (float)h1[j]; u2[j] = (float)h2[j]; }

    float d1[8], d2[8], dbp[4] = {0.f,0.f,0.f,0.f};
#pragma unroll
    for (int i = 0; i < NC; ++i) {
        float w = bcw[i];
        float a = -u1[i], bb = b[i & 3], c = u2[i];
        float m = fmaxf(a, fmaxf(bb, c));
        float e0 = __expf(a - m);
        float e1 = __expf(bb - m);
        float e2 = __expf(c - m);
        float inv = 1.0f / (e0 + e1 + e2);
        d1[i] = -w * e0 * inv;
        d2[i] =  w * e2 * inv;
        dbp[i & 3] += w * e1 * inv;
    }
    float* r1 = out_u + (size_t)i1 * NU;
#pragma unroll
    for (int i = 0; i < NC; ++i) atomicAdd(r1 + i, d1[i]);
    float* r2 = out_u + (size_t)i2 * NU;
#pragma unroll
    for (int i = 0; i < NC; ++i) atomicAdd(r2 + i, d2[i]);

    float4 ob;
    ob.x = b[0] + dbp[0];
    ob.y = b[1] + dbp[1];
    ob.z = b[2] + dbp[2];
    ob.w = b[3] + dbp[3];
    ((float4*)out_b)[e] = ob;
}

extern "C" void kernel_launch(void* const* d_in, const int* in_sizes, int n_in,
                              void* d_out, int out_size, void* d_ws, size_t ws_size,
                              hipStream_t stream) {
    const float* unary  = (const float*)d_in[0];
    const float* binary = (const float*)d_in[1];
    const float* ucw    = (const float*)d_in[2];
    const float* bcw    = (const float*)d_in[3];
    const int*   index1 = (const int*)d_in[4];
    const int*   index2 = (const int*)d_in[5];

    int n_nodes = in_sizes[0] / NU;
    int n_edges = in_sizes[4];

    float* out_u = (float*)d_out;
    float* out_b = out_u + (size_t)n_nodes * NU;

    int T = (int)(((unsigned)n_nodes + TILE_N - 1) / TILE_N);   // 250
    int chunk = (n_edges + NB - 1) / NB;                        // 6250

    // ws layout: u_lo [n_nodes*8 f16] | entries [T*NB*CAP*3 u32] | counts [T*NB u32]
    size_t u_lo_bytes  = (size_t)n_nodes * 8 * sizeof(_Float16);
    size_t ent_off     = (u_lo_bytes + 63) & ~(size_t)63;
    size_t ent_bytes   = (size_t)T * NB * CAP * 12;
    size_t cnt_off     = ent_off + ent_bytes;
    size_t cnt_bytes   = (size_t)T * NB * 4;
    size_t need        = cnt_off + cnt_bytes;

    _Float16* u_lo = (_Float16*)d_ws;
    unsigned* entries = (unsigned*)((char*)d_ws + ent_off);
    unsigned* counts  = (unsigned*)((char*)d_ws + cnt_off);

    // lambda = 2*chunk/T must stay <= 50 for CAP=70 (+2.8 sigma)
    bool fast = (ws_size >= need && T <= 256 && 2 * chunk <= 50 * T);

    int tb = 256;
    unary_enhance_kernel<<<(n_nodes + tb - 1) / tb, tb, 0, stream>>>(
        unary, ucw, out_u, u_lo, n_nodes);

    if (fast) {
        bin_edges_kernel<<<NB, BT, 0, stream>>>(
            binary, bcw, index1, index2, u_lo, out_b,
            counts, entries, out_u, n_edges, T, chunk);
        tile_acc_kernel<<<T, BTA, 0, stream>>>(
            counts, entries, out_u, n_nodes);
    } else {
        edge_enhance_kernel<<<(n_edges + tb - 1) / tb, tb, 0, stream>>>(
            binary, bcw, index1, index2, u_lo, out_u, out_b, n_edges);
    }
}